// Round 2
// baseline (413.084 us; speedup 1.0000x reference)
//
#include <hip/hip_runtime.h>

// DrawRope: out[B,T,200,200,3] as INT32 (uint8 reference values 0/128/255 -> int path).
// B*T = 800 frames; per frame: zero image, draw 2 Bresenham segments (val 128),
// then endpoints p0,p1 red (255,0,0) and p2 green (0,255,0), in that order.

#define IMAGE_H 200
#define IMAGE_W 200
#define FRAME_INTS (IMAGE_H * IMAGE_W * 3)  // 120000
#define FRAME_I4   (FRAME_INTS / 4)         // 30000

__device__ __forceinline__ void draw_segment(int* img, int c0, int r0, int c1, int r1) {
    // Exact replica of the reference Bresenham (inclusive endpoints).
    int dx = abs(c1 - c0);
    int dy = -abs(r1 - r0);
    int sc = (c0 < c1) ? 1 : -1;
    int sr = (r0 < r1) ? 1 : -1;
    int err = dx + dy;
    int c = c0, r = r0;
    while (true) {
        int* p = img + (r * IMAGE_W + c) * 3;
        p[0] = 128; p[1] = 128; p[2] = 128;
        if (c == c1 && r == r1) break;
        int e2 = 2 * err;
        if (e2 >= dy) { err += dy; c += sc; }
        if (e2 <= dx) { err += dx; r += sr; }
    }
}

__global__ __launch_bounds__(256)
void draw_rope_kernel(const float* __restrict__ x,
                      const float* __restrict__ resolution,
                      const float* __restrict__ origin,
                      int* __restrict__ out) {
    const int m = blockIdx.x;  // frame index in [0, B*T)
    int* img = out + (size_t)m * FRAME_INTS;

    // Phase 1: zero this frame with coalesced int4 stores (16 B/lane).
    int4* img4 = (int4*)img;
    for (int i = threadIdx.x; i < FRAME_I4; i += 256) {
        img4[i] = make_int4(0, 0, 0, 0);
    }
    __syncthreads();

    // Phase 2: rasterize. Points -> pixel indices, exactly as reference (fp32):
    // row = floor(y/res0 + org0), col = floor(x/res1 + org1).
    const float res0 = resolution[0];
    const float res1 = resolution[1];
    const float org0 = origin[0];
    const float org1 = origin[1];
    const float* xp = x + (size_t)m * 6;

    int rows[3], cols[3];
#pragma unroll
    for (int i = 0; i < 3; ++i) {
        const float px = xp[2 * i + 0];
        const float py = xp[2 * i + 1];
        rows[i] = (int)floorf(py / res0 + org0);
        cols[i] = (int)floorf(px / res1 + org1);
    }

    // Two segments: p0->p1 (thread 0) and p1->p2 (thread 1). All writes = 128,
    // so overlap between the two segments is benign.
    if (threadIdx.x < 2) {
        const int s = threadIdx.x;
        draw_segment(img, cols[s], rows[s], cols[s + 1], rows[s + 1]);
    }
    __syncthreads();  // order line writes before endpoint overwrites

    // Phase 3: endpoints, reference scatter order (red p0, red p1, green p2).
    if (threadIdx.x == 0) {
        int* p0 = img + (rows[0] * IMAGE_W + cols[0]) * 3;
        p0[0] = 255; p0[1] = 0; p0[2] = 0;
        int* p1 = img + (rows[1] * IMAGE_W + cols[1]) * 3;
        p1[0] = 255; p1[1] = 0; p1[2] = 0;
        int* p2 = img + (rows[2] * IMAGE_W + cols[2]) * 3;
        p2[0] = 0; p2[1] = 255; p2[2] = 0;
    }
}

extern "C" void kernel_launch(void* const* d_in, const int* in_sizes, int n_in,
                              void* d_out, int out_size, void* d_ws, size_t ws_size,
                              hipStream_t stream) {
    const float* x          = (const float*)d_in[0];  // [B,T,6]
    const float* resolution = (const float*)d_in[1];  // [2]
    const float* origin     = (const float*)d_in[2];  // [2]
    int* out                = (int*)d_out;            // [B,T,200,200,3] int32

    const int M = in_sizes[0] / 6;  // B*T = 800 frames
    draw_rope_kernel<<<M, 256, 0, stream>>>(x, resolution, origin, out);
}

// Round 3
// 406.653 us; speedup vs baseline: 1.0158x; 1.0158x over previous
//
#include <hip/hip_runtime.h>

// DrawRope: out[B,T,200,200,3] as INT32 (uint8 reference values 0/128/255 -> int path).
// Strategy: hipMemsetAsync zero-fill (rocclr fill kernel, ~5.9 TB/s measured on this
// machine) + a tiny draw kernel (800 blocks x 1 wave) for lines/endpoints.

#define IMAGE_H 200
#define IMAGE_W 200
#define FRAME_INTS (IMAGE_H * IMAGE_W * 3)  // 120000

__device__ __forceinline__ void draw_segment(int* img, int c0, int r0, int c1, int r1) {
    // Exact replica of the reference Bresenham (inclusive endpoints).
    int dx = abs(c1 - c0);
    int dy = -abs(r1 - r0);
    int sc = (c0 < c1) ? 1 : -1;
    int sr = (r0 < r1) ? 1 : -1;
    int err = dx + dy;
    int c = c0, r = r0;
    while (true) {
        int* p = img + (r * IMAGE_W + c) * 3;
        p[0] = 128; p[1] = 128; p[2] = 128;
        if (c == c1 && r == r1) break;
        int e2 = 2 * err;
        if (e2 >= dy) { err += dy; c += sc; }
        if (e2 <= dx) { err += dx; r += sr; }
    }
}

__global__ __launch_bounds__(64)
void draw_rope_lines(const float* __restrict__ x,
                     const float* __restrict__ resolution,
                     const float* __restrict__ origin,
                     int* __restrict__ out) {
    const int m = blockIdx.x;  // frame index in [0, B*T)
    int* img = out + (size_t)m * FRAME_INTS;

    // Points -> pixel indices, exactly as reference (fp32):
    // row = floor(y/res0 + org0), col = floor(x/res1 + org1).
    const float res0 = resolution[0];
    const float res1 = resolution[1];
    const float org0 = origin[0];
    const float org1 = origin[1];
    const float* xp = x + (size_t)m * 6;

    int rows[3], cols[3];
#pragma unroll
    for (int i = 0; i < 3; ++i) {
        rows[i] = (int)floorf(xp[2 * i + 1] / res0 + org0);
        cols[i] = (int)floorf(xp[2 * i + 0] / res1 + org1);
    }

    // Lanes 0,1: segments p0->p1 and p1->p2. All line writes are 128, so
    // overlap between the two segments is benign.
    if (threadIdx.x < 2) {
        const int s = threadIdx.x;
        draw_segment(img, cols[s], rows[s], cols[s + 1], rows[s + 1]);
    }
    __syncthreads();  // drain line stores before endpoint overwrites (single wave: cheap)

    // Endpoints in reference scatter order (red p0, red p1, green p2).
    if (threadIdx.x == 0) {
        int* p0 = img + (rows[0] * IMAGE_W + cols[0]) * 3;
        p0[0] = 255; p0[1] = 0; p0[2] = 0;
        int* p1 = img + (rows[1] * IMAGE_W + cols[1]) * 3;
        p1[0] = 255; p1[1] = 0; p1[2] = 0;
        int* p2 = img + (rows[2] * IMAGE_W + cols[2]) * 3;
        p2[0] = 0; p2[1] = 255; p2[2] = 0;
    }
}

extern "C" void kernel_launch(void* const* d_in, const int* in_sizes, int n_in,
                              void* d_out, int out_size, void* d_ws, size_t ws_size,
                              hipStream_t stream) {
    const float* x          = (const float*)d_in[0];  // [B,T,6]
    const float* resolution = (const float*)d_in[1];  // [2]
    const float* origin     = (const float*)d_in[2];  // [2]
    int* out                = (int*)d_out;            // [B,T,200,200,3] int32

    const int M = in_sizes[0] / 6;  // B*T = 800 frames

    // Zero the whole output with the tuned rocclr fill kernel (~5.9 TB/s measured).
    hipMemsetAsync(d_out, 0, (size_t)out_size * sizeof(int), stream);

    // Then rasterize lines + endpoints (touches ~4 KB per frame).
    draw_rope_lines<<<M, 64, 0, stream>>>(x, resolution, origin, out);
}